// Round 1
// baseline (1155.680 us; speedup 1.0000x reference)
//
#include <hip/hip_runtime.h>
#include <math.h>

#define BLOCK 256
#define NBINS 2048
#define CAP 512
#define KTOP 100
#define TEMP 5.0f
#define LAMBDA_TCS 10.0f
#define IGNORE_INDEX (-100)

// Monotonic float->uint mapping: order-preserving for all finite floats.
__device__ __forceinline__ unsigned key_of(float f) {
    unsigned u = __float_as_uint(f);
    return u ^ ((unsigned)((int)u >> 31) | 0x80000000u);
}
__device__ __forceinline__ float val_of(unsigned key) {
    unsigned u = (key & 0x80000000u) ? (key ^ 0x80000000u) : ~key;
    return __uint_as_float(u);
}

__device__ __forceinline__ void lse_acc(float& m, float& s, float v) {
    float mn = fmaxf(m, v);
    s = s * __expf(m - mn) + __expf(v - mn);
    m = mn;
}

__device__ __forceinline__ float block_sum(float v, float* red) {
    for (int off = 32; off; off >>= 1) v += __shfl_down(v, off);
    __syncthreads();
    if ((threadIdx.x & 63) == 0) red[threadIdx.x >> 6] = v;
    __syncthreads();
    return red[0] + red[1] + red[2] + red[3];
}
__device__ __forceinline__ float block_max(float v, float* red) {
    for (int off = 32; off; off >>= 1) v = fmaxf(v, __shfl_down(v, off));
    __syncthreads();
    if ((threadIdx.x & 63) == 0) red[threadIdx.x >> 6] = v;
    __syncthreads();
    return fmaxf(fmaxf(red[0], red[1]), fmaxf(red[2], red[3]));
}

__global__ __launch_bounds__(BLOCK) void tcs_main(
    const float* __restrict__ S, const float* __restrict__ T,
    const int* __restrict__ L, float* __restrict__ acc, int V, int tokens)
{
    const int tok = blockIdx.x;
    if (tok >= tokens) return;
    const int tid = threadIdx.x;
    const size_t row = (size_t)tok * (size_t)V;
    const float* srow = S + row;
    const float* trow = T + row;

    __shared__ unsigned hist[NBINS];
    __shared__ unsigned chunk[BLOCK];
    __shared__ unsigned candKey[CAP];
    __shared__ int candIdx[CAP];
    __shared__ unsigned selKey[128];
    __shared__ int selIdx[128];
    __shared__ float red[4];
    __shared__ float redM[4], redS[4];
    __shared__ int s_candCount, s_selCount;
    __shared__ unsigned s_lowBound, s_countGE, s_cGT;
    __shared__ int s_shift;

    for (int i = tid; i < NBINS; i += BLOCK) hist[i] = 0;
    __syncthreads();

    // ---- Pass A: student online logsumexp + teacher 11-bit histogram ----
    float m = -INFINITY, ssum = 0.0f;
    const int V4 = V >> 2;
    const float4* s4 = (const float4*)srow;
    const float4* t4 = (const float4*)trow;
    for (int i = tid; i < V4; i += BLOCK) {
        float4 sv = s4[i];
        float4 tv = t4[i];
        lse_acc(m, ssum, sv.x); lse_acc(m, ssum, sv.y);
        lse_acc(m, ssum, sv.z); lse_acc(m, ssum, sv.w);
        atomicAdd(&hist[key_of(tv.x) >> 21], 1u);
        atomicAdd(&hist[key_of(tv.y) >> 21], 1u);
        atomicAdd(&hist[key_of(tv.z) >> 21], 1u);
        atomicAdd(&hist[key_of(tv.w) >> 21], 1u);
    }
    for (int i = (V4 << 2) + tid; i < V; i += BLOCK) {
        lse_acc(m, ssum, srow[i]);
        atomicAdd(&hist[key_of(trow[i]) >> 21], 1u);
    }

    // wave-level (m,s) reduce, then cross-wave
    for (int off = 32; off; off >>= 1) {
        float m2 = __shfl_down(m, off);
        float s2 = __shfl_down(ssum, off);
        float mn = fmaxf(m, m2);
        ssum = ssum * __expf(m - mn) + s2 * __expf(m2 - mn);
        m = mn;
    }
    if ((tid & 63) == 0) { redM[tid >> 6] = m; redS[tid >> 6] = ssum; }
    __syncthreads();   // also closes histogram atomics

    float nll = 0.0f;
    bool valid = false;
    if (tid == 0) {
        float mm = redM[0], ss = redS[0];
        for (int w = 1; w < 4; ++w) {
            float mn = fmaxf(mm, redM[w]);
            ss = ss * __expf(mm - mn) + redS[w] * __expf(redM[w] - mn);
            mm = mn;
        }
        int lab = L[tok];
        valid = (lab != IGNORE_INDEX);
        float sl = 0.0f;
        if (valid && lab >= 0 && lab < V) sl = srow[lab];
        nll = (mm + __logf(ss)) - sl;   // -log_softmax at label
    }

    // ---- radix-select scan: find bin containing the KTOP-th largest ----
    unsigned csum = 0;
    for (int b = tid * 8; b < tid * 8 + 8; ++b) csum += hist[b];
    chunk[tid] = csum;
    __syncthreads();
    if (tid == 0) {
        unsigned accum = 0; int csel = 0;
        for (int c = BLOCK - 1; c >= 0; --c) {
            if (accum + chunk[c] >= (unsigned)KTOP) { csel = c; break; }
            accum += chunk[c];
        }
        int bsel = csel * 8;
        for (int b = csel * 8 + 7; b >= csel * 8; --b) {
            if (accum + hist[b] >= (unsigned)KTOP) { bsel = b; break; }
            accum += hist[b];
        }
        s_cGT = accum;                      // count strictly above selected bin
        s_countGE = accum + hist[bsel];     // candidates >= bin lower bound
        s_lowBound = (unsigned)bsel << 21;
        s_shift = 21;
    }

    // ---- refinement (rare for N(0,1) data): narrow until candidates <= CAP ----
    while (true) {
        __syncthreads();
        if (s_countGE <= (unsigned)CAP || s_shift == 0) break;
        const int shift = s_shift;
        const int nextShift = (shift >= 11) ? (shift - 11) : 0;
        const int nb = 1 << (shift - nextShift);
        const unsigned prefix = s_lowBound >> shift;
        const unsigned cGT_in = s_cGT;
        __syncthreads();
        for (int i = tid; i < nb; i += BLOCK) hist[i] = 0;
        __syncthreads();
        for (int i = tid; i < V; i += BLOCK) {
            unsigned key = key_of(trow[i]);
            if ((key >> shift) == prefix)
                atomicAdd(&hist[(key >> nextShift) & (nb - 1)], 1u);
        }
        __syncthreads();
        if (tid == 0) {
            unsigned kRem = (unsigned)KTOP - cGT_in;
            unsigned accum = 0; int bsel = 0;
            for (int b = nb - 1; b >= 0; --b) {
                if (accum + hist[b] >= kRem) { bsel = b; break; }
                accum += hist[b];
            }
            s_cGT = cGT_in + accum;
            s_countGE = s_cGT + hist[bsel];
            s_lowBound |= (unsigned)bsel << nextShift;
            s_shift = nextShift;
        }
    }

    // ---- collect candidates (key >= lowBound) ----
    if (tid == 0) s_candCount = 0;
    __syncthreads();
    const unsigned lowB = s_lowBound;
    for (int i = tid; i < V4; i += BLOCK) {
        float4 tv = t4[i];
        unsigned k0 = key_of(tv.x), k1 = key_of(tv.y);
        unsigned k2 = key_of(tv.z), k3 = key_of(tv.w);
        int base = i << 2;
        if (k0 >= lowB) { int p = atomicAdd(&s_candCount, 1); if (p < CAP) { candKey[p] = k0; candIdx[p] = base; } }
        if (k1 >= lowB) { int p = atomicAdd(&s_candCount, 1); if (p < CAP) { candKey[p] = k1; candIdx[p] = base + 1; } }
        if (k2 >= lowB) { int p = atomicAdd(&s_candCount, 1); if (p < CAP) { candKey[p] = k2; candIdx[p] = base + 2; } }
        if (k3 >= lowB) { int p = atomicAdd(&s_candCount, 1); if (p < CAP) { candKey[p] = k3; candIdx[p] = base + 3; } }
    }
    for (int i = (V4 << 2) + tid; i < V; i += BLOCK) {
        unsigned k0 = key_of(trow[i]);
        if (k0 >= lowB) { int p = atomicAdd(&s_candCount, 1); if (p < CAP) { candKey[p] = k0; candIdx[p] = i; } }
    }
    __syncthreads();
    int M = s_candCount; if (M > CAP) M = CAP;

    // ---- exact top-K among M candidates via O(M^2) ranking (idx tie-break) ----
    if (tid == 0) s_selCount = 0;
    __syncthreads();
    for (int c = tid; c < M; c += BLOCK) {
        unsigned kc = candKey[c]; int ic = candIdx[c];
        int rank = 0;
        for (int j = 0; j < M; ++j) {
            unsigned kj = candKey[j];
            if (kj > kc || (kj == kc && candIdx[j] < ic)) ++rank;
        }
        if (rank < KTOP) {
            int p = atomicAdd(&s_selCount, 1);
            if (p < 128) { selKey[p] = kc; selIdx[p] = ic; }
        }
    }
    __syncthreads();
    const int n = min(s_selCount, 128);

    // ---- temperature KL over the selected top-K ----
    float x = -INFINITY, y = -INFINITY;
    if (tid < n) {
        x = val_of(selKey[tid]) * (1.0f / TEMP);
        y = srow[selIdx[tid]] * (1.0f / TEMP);
    }
    float mx = block_max(x, red);
    float my = block_max(y, red);
    float ex = (tid < n) ? __expf(x - mx) : 0.0f;
    float Zt = block_sum(ex, red);
    float ey = (tid < n) ? __expf(y - my) : 0.0f;
    float Zs = block_sum(ey, red);
    float lZt = __logf(Zt), lZs = __logf(Zs);
    float kli = (tid < n) ? (ex / Zt) * ((x - mx - lZt) - (y - my - lZs)) : 0.0f;
    float kl = block_sum(kli, red);

    if (tid == 0 && valid) {
        atomicAdd(&acc[0], nll);
        atomicAdd(&acc[1], kl);
        atomicAdd(&acc[2], 1.0f);
    }
}

__global__ void tcs_finalize(const float* __restrict__ acc, float* __restrict__ out) {
    float cnt = fmaxf(acc[2], 1.0f);
    float ce = acc[0] / cnt;
    float tcs = acc[1] / cnt * (TEMP * TEMP);
    out[0] = ce + LAMBDA_TCS * tcs;
    out[1] = ce;
    out[2] = tcs;
    out[3] = 0.0f;
}

extern "C" void kernel_launch(void* const* d_in, const int* in_sizes, int n_in,
                              void* d_out, int out_size, void* d_ws, size_t ws_size,
                              hipStream_t stream) {
    const float* S = (const float*)d_in[0];
    const float* T = (const float*)d_in[1];
    const int* L = (const int*)d_in[2];
    const int tokens = in_sizes[2];
    const int V = in_sizes[0] / tokens;
    float* acc = (float*)d_ws;
    hipMemsetAsync(acc, 0, 4 * sizeof(float), stream);
    tcs_main<<<tokens, BLOCK, 0, stream>>>(S, T, L, acc, V, tokens);
    tcs_finalize<<<1, 1, 0, stream>>>(acc, (float*)d_out);
}